// Round 4
// baseline (166.330 us; speedup 1.0000x reference)
//
#include <hip/hip_runtime.h>

// hybridloss: arcface CE (512x100000x128 bf16-MFMA GEMM + exp-sum softmax)
//           + TV loss + bin loss + sum|FFT2(k)| (1024x1024 radix-2 DIF, bit-reversed
//             order OK — final sum is permutation-invariant).
// R4: gemm restructured for latency: (1) label/OUTN masks removed from epilogue —
//     sum ALL cols (pad rows give exp2(0)=1 -> subtract 96; label col subtracted in
//     final via fp32 re-dot of same bf16 operands); (2) grid (782 o)x(4 bt) with
//     o=bid>>2 swizzle for Wh L2 reuse; (3) XOR-swizzled LDS tiles (32.8KB union,
//     4 blocks/CU via __launch_bounds__(256,4)), zero bank-conflict layout;
//     (4) per-wave-pair gpart rows -> no LDS atomics, 1 barrier pair per K-chunk;
//     (5) fftcol uses interleaved float2 LDS.
// Workspace layout (bytes), total 35,800,064 (ws is 256 MiB):
//   [0,2048)              coslab[512]
//   [2048,133120)         xh: 512x128 bf16
//   [133120,25757696)     Wh: 100096x128 bf16 (pad rows zeroed)
//   [25757696,34146304)   fbuf: 1024x1024 float2
//   [34146304,35350528)   gpart[1564][512]  (782 o-tiles x 2 wave-halves)
//   [35350528,35383296)   g2[16][512]
//   [35383296,35399680)   tvpart[1024] float4
//   [35399680,35400704)   fftpart[256]
//   [35400704,35402752)   labexp[512]

typedef short bf16x8 __attribute__((ext_vector_type(8)));
typedef float f32x4 __attribute__((ext_vector_type(4)));
typedef unsigned short u16;
typedef unsigned int u32;

#define BATCH 512
#define DIM 128
#define OUTN 100000
#define OUTPAD 100096   // 782 * 128
#define NOBLK 782
#define GEMMBLK 3128    // 782 * 4
#define NROW2 1564      // gpart rows
#define CHUNKS 16
#define CHSZ2 98        // 16*98 = 1568 >= 1564
#define SSCALE 32.0f
#define K2C 46.166241308446828f   // 32 * log2(e)
#define COSM 0.8775825618903728f
#define SINM 0.479425538604203f
#define THC (-0.8775825618903728f)
#define MMC 0.2397127693021015f

// stage1 role boundaries (blockIdx.x)
#define S1_FFT 1024
#define S1_TV  2048
#define S1_XP  2176
#define S1_NW  27200   // 2176 + 25024

__device__ inline u16 f2bf(float f) {
  union { float f; u32 u; } v; v.f = f;
  u32 r = v.u + 0x7FFFu + ((v.u >> 16) & 1u);   // round-to-nearest-even
  return (u16)(r >> 16);
}

__device__ inline float waveRedSum(float v) {
#pragma unroll
  for (int off = 1; off < 64; off <<= 1) v += __shfl_xor(v, off, 64);
  return v;
}

// ---------------- stage 1: fftrow | tvbin | xprep | normW ----------------
__global__ __launch_bounds__(256) void stage1_k(const float* __restrict__ x,
                                                const float* __restrict__ W,
                                                const int* __restrict__ label,
                                                const float* __restrict__ kimg,
                                                u32* __restrict__ xh,
                                                float* __restrict__ coslab,
                                                u32* __restrict__ Wh,
                                                float4* __restrict__ tvpart,
                                                float2* __restrict__ fbuf) {
  __shared__ __align__(16) float smem[2064];
  int t = threadIdx.x;
  int bid = blockIdx.x;

  if (bid < S1_FFT) {
    // ---- row FFT: 1024-pt radix-2 DIF (bit-reversed out, fine) ----
    float* re = smem;
    float* im = smem + 1024;
    int r = bid;
#pragma unroll
    for (int i = 0; i < 4; i++) {
      int idx = i * 256 + t;
      re[idx] = kimg[r * 1024 + idx];
      im[idx] = 0.f;
    }
    __syncthreads();
    for (int lh = 9; lh >= 0; lh--) {
      int hlf = 1 << lh;
      float ang = -6.283185307179586f / (float)(hlf * 2);
#pragma unroll
      for (int i = 0; i < 2; i++) {
        int bf = i * 256 + t;
        int pos = bf & (hlf - 1);
        int g = bf >> lh;
        int i0 = (g << (lh + 1)) + pos;
        int i1 = i0 + hlf;
        float ur = re[i0], ui = im[i0], vr = re[i1], vi = im[i1];
        float s, c;
        __sincosf(ang * (float)pos, &s, &c);
        re[i0] = ur + vr; im[i0] = ui + vi;
        float dr = ur - vr, di = ui - vi;
        re[i1] = dr * c - di * s;
        im[i1] = dr * s + di * c;
      }
      __syncthreads();
    }
#pragma unroll
    for (int i = 0; i < 4; i++) {
      int idx = i * 256 + t;
      fbuf[(size_t)r * 1024 + idx] = make_float2(re[idx], im[idx]);
    }
  } else if (bid < S1_TV) {
    // ---- TV + bin loss, one image row per block ----
    int r = bid - S1_FFT;
    int idx = r * 1024 + t * 4;
    float4 v = *(const float4*)&kimg[idx];
    float bs = v.x * v.x + (v.x - 1.f) * (v.x - 1.f)
             + v.y * v.y + (v.y - 1.f) * (v.y - 1.f)
             + v.z * v.z + (v.z - 1.f) * (v.z - 1.f)
             + v.w * v.w + (v.w - 1.f) * (v.w - 1.f);
    float d0 = v.y - v.x, d1 = v.z - v.y, d2 = v.w - v.z;
    float wsm = d0 * d0 + d1 * d1 + d2 * d2;
    if (t < 255) { float e4 = kimg[idx + 4]; float d3 = e4 - v.w; wsm += d3 * d3; }
    float hs = 0.f;
    if (r < 1023) {
      float4 n = *(const float4*)&kimg[idx + 1024];
      float h0 = n.x - v.x, h1 = n.y - v.y, h2 = n.z - v.z, h3 = n.w - v.w;
      hs = h0 * h0 + h1 * h1 + h2 * h2 + h3 * h3;
    }
    hs = waveRedSum(hs); wsm = waveRedSum(wsm); bs = waveRedSum(bs);
    float (*red)[4] = (float(*)[4])smem;
    if ((t & 63) == 0) { int w = t >> 6; red[0][w] = hs; red[1][w] = wsm; red[2][w] = bs; }
    __syncthreads();
    if (t == 0)
      tvpart[r] = make_float4(red[0][0] + red[0][1] + red[0][2] + red[0][3],
                              red[1][0] + red[1][1] + red[1][2] + red[1][3],
                              red[2][0] + red[2][1] + red[2][2] + red[2][3], 0.f);
  } else if (bid < S1_XP) {
    // ---- x normalize -> bf16 + cosine(x_b, W[label_b]) ----
    int b = (bid - S1_TV) * 4 + (t >> 6);
    int lane = t & 63;
    size_t xb = (size_t)b * DIM;
    float2 v = *(const float2*)&x[xb + lane * 2];
    int lab = label[b];
    size_t wb = (size_t)lab * DIM;
    float2 w = *(const float2*)&W[wb + lane * 2];
    float ss = waveRedSum(v.x * v.x + v.y * v.y);
    float d  = waveRedSum(v.x * w.x + v.y * w.y);
    float nw = waveRedSum(w.x * w.x + w.y * w.y);
    float inv = rsqrtf(ss);
    xh[b * 64 + lane] = (u32)f2bf(v.x * inv) | ((u32)f2bf(v.y * inv) << 16);
    if (lane == 0) coslab[b] = d * rsqrtf(ss * nw);
  } else {
    // ---- W normalize -> bf16 (packed u32); pad rows -> 0 ----
    int row = (bid - S1_XP) * 4 + (t >> 6);
    int lane = t & 63;
    size_t base = (size_t)row * DIM;
    if (row < OUTN) {
      float2 v = *(const float2*)&W[base + lane * 2];
      float ss = waveRedSum(v.x * v.x + v.y * v.y);
      float inv = rsqrtf(ss);
      Wh[row * 64 + lane] = (u32)f2bf(v.x * inv) | ((u32)f2bf(v.y * inv) << 16);
    } else {
      Wh[row * 64 + lane] = 0;
    }
  }
}

// ---------------- stage 2: gemm (o=bid>>2 swizzle) | fftcol ----------------
__global__ __launch_bounds__(256, 4) void stage2_k(const u16* __restrict__ Wh,
                                                   const u16* __restrict__ xh,
                                                   float* __restrict__ gpart,
                                                   const float2* __restrict__ fbuf,
                                                   float* __restrict__ fftpart) {
  __shared__ __align__(16) char smem[32784];
  int t = threadIdx.x;
  int bid = blockIdx.x;

  if (bid < GEMMBLK) {
    // ---- GEMM role: 128(o) x 128(b), K=128 in 2 chunks, XOR-swizzled LDS ----
    int o = bid >> 2, bt = bid & 3;       // 4 consecutive blocks share the Wh o-tile
    int o0 = o * 128, b0 = bt * 128;
    u16* Ash = (u16*)smem;                // 128 rows x 64 u16, 16B chunks XOR (row&7)
    u16* Bsh = (u16*)(smem + 16384);
    int wv = t >> 6, lane = t & 63;
    int wo = (wv & 1) << 6, wbs = (wv >> 1) << 6;
    int m16 = lane & 15, q = lane >> 4;
    f32x4 acc[4][4] = {};

#pragma unroll
    for (int kc = 0; kc < 2; kc++) {
      if (kc) __syncthreads();            // WAR: previous chunk's reads done
#pragma unroll
      for (int i = 0; i < 4; i++) {
        int f = i * 256 + t;
        int rr = f >> 3, gg = f & 7;
        int sw = ((gg ^ (rr & 7)) * 8);
        *(uint4*)&Ash[rr * 64 + sw] =
            *(const uint4*)&Wh[(size_t)(o0 + rr) * DIM + kc * 64 + gg * 8];
        *(uint4*)&Bsh[rr * 64 + sw] =
            *(const uint4*)&xh[(size_t)(b0 + rr) * DIM + kc * 64 + gg * 8];
      }
      __syncthreads();
#pragma unroll
      for (int kk = 0; kk < 2; kk++) {
        bf16x8 af[4], bfr[4];
#pragma unroll
        for (int i = 0; i < 4; i++) {
          int row = wo + i * 16 + m16;
          af[i] = *(const bf16x8*)&Ash[row * 64 + (((kk * 4 + q) ^ (row & 7)) * 8)];
        }
#pragma unroll
        for (int j = 0; j < 4; j++) {
          int row = wbs + j * 16 + m16;
          bfr[j] = *(const bf16x8*)&Bsh[row * 64 + (((kk * 4 + q) ^ (row & 7)) * 8)];
        }
#pragma unroll
        for (int i = 0; i < 4; i++)
#pragma unroll
          for (int j = 0; j < 4; j++)
            acc[i][j] = __builtin_amdgcn_mfma_f32_16x16x32_bf16(af[i], bfr[j], acc[i][j], 0, 0, 0);
      }
    }
    // Epilogue: unmasked exp2 sum over this block's 128 o's; per-wave-pair rows.
#pragma unroll
    for (int j = 0; j < 4; j++) {
      float s = 0.f;
#pragma unroll
      for (int i = 0; i < 4; i++)
#pragma unroll
        for (int r = 0; r < 4; r++)
          s += exp2f(K2C * acc[i][j][r]);
      s += __shfl_xor(s, 16, 64);   // fold q-quadrants (same b, different o)
      s += __shfl_xor(s, 32, 64);
      if (q == 0)
        gpart[(size_t)(o * 2 + (wv & 1)) * 512 + b0 + wbs + j * 16 + m16] = s;
    }
  } else {
    // ---- column FFT role: 4 cols/block, interleaved float2 LDS ----
    float2* arr = (float2*)smem;          // 4096 float2 = 32 KB
    float* red = (float*)(smem + 32768);
    int c0 = (bid - GEMMBLK) * 4;
#pragma unroll
    for (int i = 0; i < 16; i++) {
      int li = i * 256 + t;
      int rr = li >> 2, c = li & 3;
      arr[rr * 4 + c] = fbuf[(size_t)rr * 1024 + c0 + c];
    }
    __syncthreads();
    for (int lh = 9; lh >= 0; lh--) {
      int hlf = 1 << lh;
      float ang = -6.283185307179586f / (float)(hlf * 2);
#pragma unroll
      for (int i = 0; i < 8; i++) {
        int w = i * 256 + t;
        int c = w & 3, bf = w >> 2;
        int pos = bf & (hlf - 1), g2i = bf >> lh;
        int i0 = ((g2i << (lh + 1)) + pos) * 4 + c;
        int i1 = i0 + hlf * 4;
        float2 u = arr[i0], v = arr[i1];
        float s, cc;
        __sincosf(ang * (float)pos, &s, &cc);
        arr[i0] = make_float2(u.x + v.x, u.y + v.y);
        float dr = u.x - v.x, di = u.y - v.y;
        arr[i1] = make_float2(dr * cc - di * s, dr * s + di * cc);
      }
      __syncthreads();
    }
    float s = 0.f;
#pragma unroll
    for (int i = 0; i < 16; i++) {
      float2 v = arr[i * 256 + t];
      s += sqrtf(v.x * v.x + v.y * v.y);
    }
    s = waveRedSum(s);
    if ((t & 63) == 0) red[t >> 6] = s;
    __syncthreads();
    if (t == 0) fftpart[bid - GEMMBLK] = red[0] + red[1] + red[2] + red[3];
  }
}

// blocks 0..31: reduce gpart[1564][512] -> g2[16][512].
// blocks 32..33: labexp[b] = exp2(K2 * fp32-dot(xh[b], Wh[label[b]])).
__global__ __launch_bounds__(256) void gemmred_k(const float* __restrict__ gpart,
                                                 float* __restrict__ g2,
                                                 const u32* __restrict__ xh32,
                                                 const u32* __restrict__ Wh32,
                                                 const int* __restrict__ label,
                                                 float* __restrict__ labexp) {
  int t = threadIdx.x;
  int blk = blockIdx.x;
  if (blk < 32) {
    int chunk = blk >> 1, half = blk & 1;
    int b = half * 256 + t;
    int rBeg = chunk * CHSZ2;
    int rEnd = rBeg + CHSZ2; if (rEnd > NROW2) rEnd = NROW2;
    float s = 0.f;
    for (int r = rBeg; r < rEnd; r++) s += gpart[(size_t)r * 512 + b];
    g2[chunk * 512 + b] = s;
  } else {
    int b = (blk - 32) * 256 + t;
    int lab = label[b];
    const u32* xr = &xh32[b * 64];
    const u32* wr = &Wh32[(size_t)lab * 64];
    float d = 0.f;
#pragma unroll 8
    for (int i = 0; i < 64; i++) {
      u32 xa = xr[i], wa = wr[i];
      float xl = __uint_as_float(xa << 16), xhp = __uint_as_float(xa & 0xFFFF0000u);
      float wl = __uint_as_float(wa << 16), whp = __uint_as_float(wa & 0xFFFF0000u);
      d += xl * wl + xhp * whp;
    }
    labexp[b] = exp2f(K2C * d);
  }
}

__global__ __launch_bounds__(256) void final_k(const float* __restrict__ coslab,
                                               const float* __restrict__ g2,
                                               const float4* __restrict__ tvpart,
                                               const float* __restrict__ fftpart,
                                               const float* __restrict__ labexp,
                                               float* __restrict__ out) {
  int t = threadIdx.x;
  float arc = 0.f, hs = 0.f, wsm = 0.f, bs = 0.f, fs = 0.f;
#pragma unroll
  for (int i = 0; i < 2; i++) {
    int b = i * 256 + t;
    float se = 0.f;
#pragma unroll
    for (int c = 0; c < CHUNKS; c++) se += g2[c * 512 + b];
    se -= 96.0f;            // OUTPAD-OUTN zero rows contribute exp2(0)=1 each
    se -= labexp[b];        // remove bf16 label column
    float cl = coslab[b];
    float sine = sqrtf(fmaxf(0.f, 1.f - cl * cl));
    float phi = cl * COSM - sine * SINM;
    if (!(cl - THC > 0.f)) phi = cl - MMC;
    arc += __logf(se + exp2f(K2C * phi)) - SSCALE * phi;
  }
#pragma unroll
  for (int i = 0; i < 4; i++) {
    float4 p = tvpart[i * 256 + t];
    hs += p.x; wsm += p.y; bs += p.z;
  }
  fs = fftpart[t];
  arc = waveRedSum(arc); hs = waveRedSum(hs); wsm = waveRedSum(wsm);
  bs = waveRedSum(bs); fs = waveRedSum(fs);
  __shared__ float red[5][4];
  if ((t & 63) == 0) {
    int w = t >> 6;
    red[0][w] = arc; red[1][w] = hs; red[2][w] = wsm; red[3][w] = bs; red[4][w] = fs;
  }
  __syncthreads();
  if (t == 0) {
    float A = 0, H = 0, Wv = 0, Bv = 0, F = 0;
#pragma unroll
    for (int w = 0; w < 4; w++) {
      A += red[0][w]; H += red[1][w]; Wv += red[2][w]; Bv += red[3][w]; F += red[4][w];
    }
    float cnt = 1023.0f * 1024.0f;
    out[0] = A * (1.0f / 512.0f) - 2.0f * (H / cnt + Wv / cnt)
           + Bv * (1.0f / 1048576.0f) + F;
  }
}

extern "C" void kernel_launch(void* const* d_in, const int* in_sizes, int n_in,
                              void* d_out, int out_size, void* d_ws, size_t ws_size,
                              hipStream_t stream) {
  const float* x = (const float*)d_in[0];
  const int* label = (const int*)d_in[1];
  const float* kimg = (const float*)d_in[2];
  // d_in[3]=x0, d_in[4]=img — unused by the reference loss
  const float* W = (const float*)d_in[5];
  float* out = (float*)d_out;
  char* ws = (char*)d_ws;
  float*  coslab  = (float*)(ws + 0);
  u32*    xh      = (u32*)(ws + 2048);
  u32*    Wh      = (u32*)(ws + 133120);
  float2* fbuf    = (float2*)(ws + 25757696);
  float*  gpart   = (float*)(ws + 34146304);
  float*  g2      = (float*)(ws + 35350528);
  float4* tvpart  = (float4*)(ws + 35383296);
  float*  fftpart = (float*)(ws + 35399680);
  float*  labexp  = (float*)(ws + 35400704);

  hipLaunchKernelGGL(stage1_k, dim3(S1_NW), dim3(256), 0, stream,
                     x, W, label, kimg, xh, coslab, Wh, tvpart, fbuf);
  hipLaunchKernelGGL(stage2_k, dim3(GEMMBLK + 256), dim3(256), 0, stream,
                     (const u16*)Wh, (const u16*)xh, gpart, fbuf, fftpart);
  hipLaunchKernelGGL(gemmred_k, dim3(34), dim3(256), 0, stream,
                     gpart, g2, xh, Wh, label, labexp);
  hipLaunchKernelGGL(final_k, dim3(1), dim3(256), 0, stream,
                     coslab, g2, tvpart, fftpart, labexp, out);
}

// Round 6
// 159.734 us; speedup vs baseline: 1.0413x; 1.0413x over previous
//
#include <hip/hip_runtime.h>

// hybridloss: arcface CE (512x100000x128 bf16-MFMA GEMM + exp-sum softmax)
//           + TV loss + bin loss + sum|FFT2(k)| (1024x1024 radix-2 DIF, bit-reversed
//             order OK — final sum is permutation-invariant).
// R6: LAYOUT FIX — R4/R5 undersized gpart (needed 3,203,072 B, reserved 1,204,224):
//     rows 588+ overran g2/tvpart/fftpart/labexp. R4 "passed" only because fftcol
//     ran last (fftpart rewritten after clobber) and tv/bin corruption (~1e1) hid
//     under the 5.5e6 threshold; R5's fftcol-first exposed it (9e7 = partial
//     fftpart clobber by o-tile 306). gpart now gets its full span; tails moved
//     past 37,349,376. All R5 scheduling kept (XCD-group swizzle, fftcol-first,
//     normW 2 rows/wave).
// Workspace layout (bytes), total 37,401,600 (ws is 256 MiB):
//   [0,2048)              coslab[512]
//   [2048,133120)         xh: 512x128 bf16
//   [133120,25757696)     Wh: 100096x128 bf16 (pad rows zeroed)
//   [25757696,34146304)   fbuf: 1024x1024 float2
//   [34146304,37349376)   gpart[1564][512]  (782 o-tiles x 2 wave-halves) = 3,203,072 B
//   [37349376,37382144)   g2[16][512]
//   [37382144,37398528)   tvpart[1024] float4
//   [37398528,37399552)   fftpart[256]
//   [37399552,37401600)   labexp[512]

typedef short bf16x8 __attribute__((ext_vector_type(8)));
typedef float f32x4 __attribute__((ext_vector_type(4)));
typedef unsigned short u16;
typedef unsigned int u32;

#define BATCH 512
#define DIM 128
#define OUTN 100000
#define OUTPAD 100096   // 782 * 128
#define NOBLK 782
#define NROW2 1564      // gpart rows
#define CHUNKS 16
#define CHSZ2 98        // 16*98 = 1568 >= 1564
#define SSCALE 32.0f
#define K2C 46.166241308446828f   // 32 * log2(e)
#define COSM 0.8775825618903728f
#define SINM 0.479425538604203f
#define THC (-0.8775825618903728f)
#define MMC 0.2397127693021015f

// stage1 role boundaries (blockIdx.x)
#define S1_FFT 1024
#define S1_TV  2048
#define S1_XP  2176
#define S1_NW  14688   // 2176 + 12512 (2 W-rows per wave)

// stage2 role boundaries: [0,256) fftcol; [256, 256+3136) gemm (98 groups of 32)
#define S2_GEMM0 256
#define S2_NBLK  3392  // 256 + 98*32

__device__ inline u16 f2bf(float f) {
  union { float f; u32 u; } v; v.f = f;
  u32 r = v.u + 0x7FFFu + ((v.u >> 16) & 1u);   // round-to-nearest-even
  return (u16)(r >> 16);
}

__device__ inline float waveRedSum(float v) {
#pragma unroll
  for (int off = 1; off < 64; off <<= 1) v += __shfl_xor(v, off, 64);
  return v;
}

__device__ inline float halfRedSum(float v) {   // reduce within each 32-lane half
#pragma unroll
  for (int off = 1; off < 32; off <<= 1) v += __shfl_xor(v, off, 64);
  return v;
}

// ---------------- stage 1: fftrow | tvbin | xprep | normW ----------------
__global__ __launch_bounds__(256) void stage1_k(const float* __restrict__ x,
                                                const float* __restrict__ W,
                                                const int* __restrict__ label,
                                                const float* __restrict__ kimg,
                                                u32* __restrict__ xh,
                                                float* __restrict__ coslab,
                                                u32* __restrict__ Wh,
                                                float4* __restrict__ tvpart,
                                                float2* __restrict__ fbuf) {
  __shared__ __align__(16) float smem[2064];
  int t = threadIdx.x;
  int bid = blockIdx.x;

  if (bid < S1_FFT) {
    // ---- row FFT: 1024-pt radix-2 DIF (bit-reversed out, fine) ----
    float* re = smem;
    float* im = smem + 1024;
    int r = bid;
#pragma unroll
    for (int i = 0; i < 4; i++) {
      int idx = i * 256 + t;
      re[idx] = kimg[r * 1024 + idx];
      im[idx] = 0.f;
    }
    __syncthreads();
    for (int lh = 9; lh >= 0; lh--) {
      int hlf = 1 << lh;
      float ang = -6.283185307179586f / (float)(hlf * 2);
#pragma unroll
      for (int i = 0; i < 2; i++) {
        int bf = i * 256 + t;
        int pos = bf & (hlf - 1);
        int g = bf >> lh;
        int i0 = (g << (lh + 1)) + pos;
        int i1 = i0 + hlf;
        float ur = re[i0], ui = im[i0], vr = re[i1], vi = im[i1];
        float s, c;
        __sincosf(ang * (float)pos, &s, &c);
        re[i0] = ur + vr; im[i0] = ui + vi;
        float dr = ur - vr, di = ui - vi;
        re[i1] = dr * c - di * s;
        im[i1] = dr * s + di * c;
      }
      __syncthreads();
    }
#pragma unroll
    for (int i = 0; i < 4; i++) {
      int idx = i * 256 + t;
      fbuf[(size_t)r * 1024 + idx] = make_float2(re[idx], im[idx]);
    }
  } else if (bid < S1_TV) {
    // ---- TV + bin loss, one image row per block ----
    int r = bid - S1_FFT;
    int idx = r * 1024 + t * 4;
    float4 v = *(const float4*)&kimg[idx];
    float bs = v.x * v.x + (v.x - 1.f) * (v.x - 1.f)
             + v.y * v.y + (v.y - 1.f) * (v.y - 1.f)
             + v.z * v.z + (v.z - 1.f) * (v.z - 1.f)
             + v.w * v.w + (v.w - 1.f) * (v.w - 1.f);
    float d0 = v.y - v.x, d1 = v.z - v.y, d2 = v.w - v.z;
    float wsm = d0 * d0 + d1 * d1 + d2 * d2;
    if (t < 255) { float e4 = kimg[idx + 4]; float d3 = e4 - v.w; wsm += d3 * d3; }
    float hs = 0.f;
    if (r < 1023) {
      float4 n = *(const float4*)&kimg[idx + 1024];
      float h0 = n.x - v.x, h1 = n.y - v.y, h2 = n.z - v.z, h3 = n.w - v.w;
      hs = h0 * h0 + h1 * h1 + h2 * h2 + h3 * h3;
    }
    hs = waveRedSum(hs); wsm = waveRedSum(wsm); bs = waveRedSum(bs);
    float (*red)[4] = (float(*)[4])smem;
    if ((t & 63) == 0) { int w = t >> 6; red[0][w] = hs; red[1][w] = wsm; red[2][w] = bs; }
    __syncthreads();
    if (t == 0)
      tvpart[r] = make_float4(red[0][0] + red[0][1] + red[0][2] + red[0][3],
                              red[1][0] + red[1][1] + red[1][2] + red[1][3],
                              red[2][0] + red[2][1] + red[2][2] + red[2][3], 0.f);
  } else if (bid < S1_XP) {
    // ---- x normalize -> bf16 + cosine(x_b, W[label_b]) ----
    int b = (bid - S1_TV) * 4 + (t >> 6);
    int lane = t & 63;
    size_t xb = (size_t)b * DIM;
    float2 v = *(const float2*)&x[xb + lane * 2];
    int lab = label[b];
    size_t wb = (size_t)lab * DIM;
    float2 w = *(const float2*)&W[wb + lane * 2];
    float ss = waveRedSum(v.x * v.x + v.y * v.y);
    float d  = waveRedSum(v.x * w.x + v.y * w.y);
    float nw = waveRedSum(w.x * w.x + w.y * w.y);
    float inv = rsqrtf(ss);
    xh[b * 64 + lane] = (u32)f2bf(v.x * inv) | ((u32)f2bf(v.y * inv) << 16);
    if (lane == 0) coslab[b] = d * rsqrtf(ss * nw);
  } else {
    // ---- W normalize -> bf16, 2 rows per wave (dwordx4 + half-wave reduce) ----
    int p = (bid - S1_XP) * 4 + (t >> 6);    // row pair index: rows 2p, 2p+1
    int lane = t & 63;
    if (2 * p >= OUTN) {                      // OUTN even -> pair-uniform validity
      *(uint2*)&Wh[(size_t)p * 128 + lane * 2] = make_uint2(0u, 0u);
      return;
    }
    float4 v = *(const float4*)&W[(size_t)p * 256 + lane * 4];  // lanes<32: row 2p
    float ss = halfRedSum(v.x * v.x + v.y * v.y + v.z * v.z + v.w * v.w);
    float inv = rsqrtf(ss);
    u32 lo = (u32)f2bf(v.x * inv) | ((u32)f2bf(v.y * inv) << 16);
    u32 hi = (u32)f2bf(v.z * inv) | ((u32)f2bf(v.w * inv) << 16);
    *(uint2*)&Wh[(size_t)p * 128 + lane * 2] = make_uint2(lo, hi);
  }
}

// ---------------- stage 2: fftcol (first) | gemm (XCD-grouped) ----------------
__global__ __launch_bounds__(256, 4) void stage2_k(const u16* __restrict__ Wh,
                                                   const u16* __restrict__ xh,
                                                   float* __restrict__ gpart,
                                                   const float2* __restrict__ fbuf,
                                                   float* __restrict__ fftpart) {
  __shared__ __align__(16) char smem[32784];
  int t = threadIdx.x;
  int bid = blockIdx.x;

  if (bid >= S2_GEMM0) {
    // ---- GEMM role: 128(o) x 128(b), K=128 in 2 chunks, XOR-swizzled LDS ----
    // Group of 32 bids = 8 o-tiles x 4 b-tiles; same-o blocks are 8 apart ->
    // same XCD under round-robin dispatch -> Wh tile served by that XCD's L2.
    int wgrp = (bid - S2_GEMM0) & 31, g = (bid - S2_GEMM0) >> 5;
    int o = g * 8 + (wgrp & 7), bt = wgrp >> 3;
    if (o >= NOBLK) return;                 // 8 dead blocks in the last group
    int o0 = o * 128, b0 = bt * 128;
    u16* Ash = (u16*)smem;                  // 128 rows x 64 u16, 16B chunks XOR (row&7)
    u16* Bsh = (u16*)(smem + 16384);
    int wv = t >> 6, lane = t & 63;
    int wo = (wv & 1) << 6, wbs = (wv >> 1) << 6;
    int m16 = lane & 15, q = lane >> 4;
    f32x4 acc[4][4] = {};

#pragma unroll
    for (int kc = 0; kc < 2; kc++) {
      if (kc) __syncthreads();              // WAR: previous chunk's reads done
#pragma unroll
      for (int i = 0; i < 4; i++) {
        int f = i * 256 + t;
        int rr = f >> 3, gg = f & 7;
        int sw = ((gg ^ (rr & 7)) * 8);
        *(uint4*)&Ash[rr * 64 + sw] =
            *(const uint4*)&Wh[(size_t)(o0 + rr) * DIM + kc * 64 + gg * 8];
        *(uint4*)&Bsh[rr * 64 + sw] =
            *(const uint4*)&xh[(size_t)(b0 + rr) * DIM + kc * 64 + gg * 8];
      }
      __syncthreads();
#pragma unroll
      for (int kk = 0; kk < 2; kk++) {
        bf16x8 af[4], bfr[4];
#pragma unroll
        for (int i = 0; i < 4; i++) {
          int row = wo + i * 16 + m16;
          af[i] = *(const bf16x8*)&Ash[row * 64 + (((kk * 4 + q) ^ (row & 7)) * 8)];
        }
#pragma unroll
        for (int j = 0; j < 4; j++) {
          int row = wbs + j * 16 + m16;
          bfr[j] = *(const bf16x8*)&Bsh[row * 64 + (((kk * 4 + q) ^ (row & 7)) * 8)];
        }
#pragma unroll
        for (int i = 0; i < 4; i++)
#pragma unroll
          for (int j = 0; j < 4; j++)
            acc[i][j] = __builtin_amdgcn_mfma_f32_16x16x32_bf16(af[i], bfr[j], acc[i][j], 0, 0, 0);
      }
    }
    // Epilogue: unmasked exp2 sum over this block's 128 o's; per-wave-pair rows.
#pragma unroll
    for (int j = 0; j < 4; j++) {
      float s = 0.f;
#pragma unroll
      for (int i = 0; i < 4; i++)
#pragma unroll
        for (int r = 0; r < 4; r++)
          s += exp2f(K2C * acc[i][j][r]);
      s += __shfl_xor(s, 16, 64);   // fold q-quadrants (same b, different o)
      s += __shfl_xor(s, 32, 64);
      if (q == 0)
        gpart[(size_t)(o * 2 + (wv & 1)) * 512 + b0 + wbs + j * 16 + m16] = s;
    }
  } else {
    // ---- column FFT role (bids 0..255, long blocks first): 4 cols/block ----
    float2* arr = (float2*)smem;            // 4096 float2 = 32 KB
    float* red = (float*)(smem + 32768);
    int c0 = bid * 4;
#pragma unroll
    for (int i = 0; i < 16; i++) {
      int li = i * 256 + t;
      int rr = li >> 2, c = li & 3;
      arr[rr * 4 + c] = fbuf[(size_t)rr * 1024 + c0 + c];
    }
    __syncthreads();
    for (int lh = 9; lh >= 0; lh--) {
      int hlf = 1 << lh;
      float ang = -6.283185307179586f / (float)(hlf * 2);
#pragma unroll
      for (int i = 0; i < 8; i++) {
        int w = i * 256 + t;
        int c = w & 3, bf = w >> 2;
        int pos = bf & (hlf - 1), g2i = bf >> lh;
        int i0 = ((g2i << (lh + 1)) + pos) * 4 + c;
        int i1 = i0 + hlf * 4;
        float2 u = arr[i0], v = arr[i1];
        float s, cc;
        __sincosf(ang * (float)pos, &s, &cc);
        arr[i0] = make_float2(u.x + v.x, u.y + v.y);
        float dr = u.x - v.x, di = u.y - v.y;
        arr[i1] = make_float2(dr * cc - di * s, dr * s + di * cc);
      }
      __syncthreads();
    }
    float s = 0.f;
#pragma unroll
    for (int i = 0; i < 16; i++) {
      float2 v = arr[i * 256 + t];
      s += sqrtf(v.x * v.x + v.y * v.y);
    }
    s = waveRedSum(s);
    if ((t & 63) == 0) red[t >> 6] = s;
    __syncthreads();
    if (t == 0) fftpart[bid] = red[0] + red[1] + red[2] + red[3];
  }
}

// blocks 0..31: reduce gpart[1564][512] -> g2[16][512].
// blocks 32..33: labexp[b] = exp2(K2 * fp32-dot(xh[b], Wh[label[b]])).
__global__ __launch_bounds__(256) void gemmred_k(const float* __restrict__ gpart,
                                                 float* __restrict__ g2,
                                                 const u32* __restrict__ xh32,
                                                 const u32* __restrict__ Wh32,
                                                 const int* __restrict__ label,
                                                 float* __restrict__ labexp) {
  int t = threadIdx.x;
  int blk = blockIdx.x;
  if (blk < 32) {
    int chunk = blk >> 1, half = blk & 1;
    int b = half * 256 + t;
    int rBeg = chunk * CHSZ2;
    int rEnd = rBeg + CHSZ2; if (rEnd > NROW2) rEnd = NROW2;
    float s = 0.f;
    for (int r = rBeg; r < rEnd; r++) s += gpart[(size_t)r * 512 + b];
    g2[chunk * 512 + b] = s;
  } else {
    int b = (blk - 32) * 256 + t;
    int lab = label[b];
    const u32* xr = &xh32[b * 64];
    const u32* wr = &Wh32[(size_t)lab * 64];
    float d = 0.f;
#pragma unroll 8
    for (int i = 0; i < 64; i++) {
      u32 xa = xr[i], wa = wr[i];
      float xl = __uint_as_float(xa << 16), xhp = __uint_as_float(xa & 0xFFFF0000u);
      float wl = __uint_as_float(wa << 16), whp = __uint_as_float(wa & 0xFFFF0000u);
      d += xl * wl + xhp * whp;
    }
    labexp[b] = exp2f(K2C * d);
  }
}

__global__ __launch_bounds__(256) void final_k(const float* __restrict__ coslab,
                                               const float* __restrict__ g2,
                                               const float4* __restrict__ tvpart,
                                               const float* __restrict__ fftpart,
                                               const float* __restrict__ labexp,
                                               float* __restrict__ out) {
  int t = threadIdx.x;
  float arc = 0.f, hs = 0.f, wsm = 0.f, bs = 0.f, fs = 0.f;
#pragma unroll
  for (int i = 0; i < 2; i++) {
    int b = i * 256 + t;
    float se = 0.f;
#pragma unroll
    for (int c = 0; c < CHUNKS; c++) se += g2[c * 512 + b];
    se -= 96.0f;            // OUTPAD-OUTN zero rows contribute exp2(0)=1 each
    se -= labexp[b];        // remove bf16 label column
    float cl = coslab[b];
    float sine = sqrtf(fmaxf(0.f, 1.f - cl * cl));
    float phi = cl * COSM - sine * SINM;
    if (!(cl - THC > 0.f)) phi = cl - MMC;
    arc += __logf(se + exp2f(K2C * phi)) - SSCALE * phi;
  }
#pragma unroll
  for (int i = 0; i < 4; i++) {
    float4 p = tvpart[i * 256 + t];
    hs += p.x; wsm += p.y; bs += p.z;
  }
  fs = fftpart[t];
  arc = waveRedSum(arc); hs = waveRedSum(hs); wsm = waveRedSum(wsm);
  bs = waveRedSum(bs); fs = waveRedSum(fs);
  __shared__ float red[5][4];
  if ((t & 63) == 0) {
    int w = t >> 6;
    red[0][w] = arc; red[1][w] = hs; red[2][w] = wsm; red[3][w] = bs; red[4][w] = fs;
  }
  __syncthreads();
  if (t == 0) {
    float A = 0, H = 0, Wv = 0, Bv = 0, F = 0;
#pragma unroll
    for (int w = 0; w < 4; w++) {
      A += red[0][w]; H += red[1][w]; Wv += red[2][w]; Bv += red[3][w]; F += red[4][w];
    }
    float cnt = 1023.0f * 1024.0f;
    out[0] = A * (1.0f / 512.0f) - 2.0f * (H / cnt + Wv / cnt)
           + Bv * (1.0f / 1048576.0f) + F;
  }
}

extern "C" void kernel_launch(void* const* d_in, const int* in_sizes, int n_in,
                              void* d_out, int out_size, void* d_ws, size_t ws_size,
                              hipStream_t stream) {
  const float* x = (const float*)d_in[0];
  const int* label = (const int*)d_in[1];
  const float* kimg = (const float*)d_in[2];
  // d_in[3]=x0, d_in[4]=img — unused by the reference loss
  const float* W = (const float*)d_in[5];
  float* out = (float*)d_out;
  char* ws = (char*)d_ws;
  float*  coslab  = (float*)(ws + 0);
  u32*    xh      = (u32*)(ws + 2048);
  u32*    Wh      = (u32*)(ws + 133120);
  float2* fbuf    = (float2*)(ws + 25757696);
  float*  gpart   = (float*)(ws + 34146304);   // 1564*512*4 = 3,203,072 B (FIXED)
  float*  g2      = (float*)(ws + 37349376);
  float4* tvpart  = (float4*)(ws + 37382144);
  float*  fftpart = (float*)(ws + 37398528);
  float*  labexp  = (float*)(ws + 37399552);

  hipLaunchKernelGGL(stage1_k, dim3(S1_NW), dim3(256), 0, stream,
                     x, W, label, kimg, xh, coslab, Wh, tvpart, fbuf);
  hipLaunchKernelGGL(stage2_k, dim3(S2_NBLK), dim3(256), 0, stream,
                     (const u16*)Wh, (const u16*)xh, gpart, fbuf, fftpart);
  hipLaunchKernelGGL(gemmred_k, dim3(34), dim3(256), 0, stream,
                     gpart, g2, xh, Wh, label, labexp);
  hipLaunchKernelGGL(final_k, dim3(1), dim3(256), 0, stream,
                     coslab, g2, tvpart, fftpart, labexp, out);
}